// Round 1
// baseline (2897.476 us; speedup 1.0000x reference)
//
#include <hip/hip_runtime.h>
#include <hip/hip_bf16.h>

#define NN 50000
#define NE 800000
#define FD 256

typedef __attribute__((ext_vector_type(8))) short bf16x8;
typedef __attribute__((ext_vector_type(4))) float f32x4;

__device__ __forceinline__ short f2bf(float f) {
    union { float f; unsigned u; } v; v.f = f;
    unsigned r = v.u + 0x7fffu + ((v.u >> 16) & 1u);
    return (short)(r >> 16);
}

// deg[row[e]] += C[e]
__global__ void deg_kernel(const int* __restrict__ row, const float* __restrict__ cv,
                           float* __restrict__ deg) {
    int e = blockIdx.x * blockDim.x + threadIdx.x;
    if (e < NE) atomicAdd(&deg[row[e]], cv[e]);
}

// deg -> deg^-1/2 in place (0 where deg<=0)
__global__ void dinv_kernel(float* __restrict__ deg) {
    int i = blockIdx.x * blockDim.x + threadIdx.x;
    if (i < NN) { float d = deg[i]; deg[i] = d > 0.f ? rsqrtf(d) : 0.f; }
}

// one wave per edge: prop[row] += w * x[col]  (64 lanes x float4 = 256 feats)
__global__ void scatter_kernel(const int* __restrict__ row, const int* __restrict__ col,
                               const float* __restrict__ cv, const float* __restrict__ dinv,
                               const float* __restrict__ x, float* __restrict__ prop) {
    int wid = (blockIdx.x * blockDim.x + threadIdx.x) >> 6;
    int lane = threadIdx.x & 63;
    if (wid >= NE) return;
    int r = row[wid], c = col[wid];
    float w = dinv[r] * cv[wid] * dinv[c];
    float4 v = *(const float4*)(x + (size_t)c * FD + lane * 4);
    float* p = prop + (size_t)r * FD + lane * 4;
    atomicAdd(p + 0, w * v.x);
    atomicAdd(p + 1, w * v.y);
    atomicAdd(p + 2, w * v.z);
    atomicAdd(p + 3, w * v.w);
}

// out = prop @ W^T + b, bf16 MFMA, one wave per 16x16 output tile
// block = 256 threads (4 waves); grid = (3125 row-tiles, 4 col-groups)
__global__ void gemm_kernel(const float* __restrict__ prop, const float* __restrict__ W,
                            const float* __restrict__ bias, float* __restrict__ out) {
    int wave = threadIdx.x >> 6;
    int lane = threadIdx.x & 63;
    int m = lane & 15;          // A-row / B-col within tile
    int g = lane >> 4;          // k-group (8 elems each)
    int row_base = blockIdx.x * 16;
    int col_base = blockIdx.y * 64 + wave * 16;

    const float* arow = prop + (size_t)(row_base + m) * FD + g * 8;
    const float* brow = W    + (size_t)(col_base + m) * FD + g * 8;  // W^T fragment

    f32x4 acc = {0.f, 0.f, 0.f, 0.f};
#pragma unroll
    for (int kk = 0; kk < 8; ++kk) {
        float4 a0 = *(const float4*)(arow + kk * 32);
        float4 a1 = *(const float4*)(arow + kk * 32 + 4);
        float4 b0 = *(const float4*)(brow + kk * 32);
        float4 b1 = *(const float4*)(brow + kk * 32 + 4);
        bf16x8 af, bf;
        af[0] = f2bf(a0.x); af[1] = f2bf(a0.y); af[2] = f2bf(a0.z); af[3] = f2bf(a0.w);
        af[4] = f2bf(a1.x); af[5] = f2bf(a1.y); af[6] = f2bf(a1.z); af[7] = f2bf(a1.w);
        bf[0] = f2bf(b0.x); bf[1] = f2bf(b0.y); bf[2] = f2bf(b0.z); bf[3] = f2bf(b0.w);
        bf[4] = f2bf(b1.x); bf[5] = f2bf(b1.y); bf[6] = f2bf(b1.z); bf[7] = f2bf(b1.w);
        acc = __builtin_amdgcn_mfma_f32_16x16x32_bf16(af, bf, acc, 0, 0, 0);
    }

    int c = col_base + m;
    float bv = bias[c];
#pragma unroll
    for (int r = 0; r < 4; ++r) {
        int rr = row_base + g * 4 + r;   // D: col=lane&15, row=(lane>>4)*4+reg
        out[(size_t)rr * FD + c] = acc[r] + bv;
    }
}

extern "C" void kernel_launch(void* const* d_in, const int* in_sizes, int n_in,
                              void* d_out, int out_size, void* d_ws, size_t ws_size,
                              hipStream_t stream) {
    const float* x  = (const float*)d_in[0];
    const int*   ei = (const int*)d_in[1];      // [2, NE]: row then col
    const float* cv = (const float*)d_in[2];
    const float* W  = (const float*)d_in[3];
    const float* b  = (const float*)d_in[4];
    float* out = (float*)d_out;

    const int* row = ei;
    const int* col = ei + NE;

    // ws layout: prop [NN*FD f32] | deg/dinv [NN f32]
    float* prop = (float*)d_ws;
    float* deg  = prop + (size_t)NN * FD;

    hipMemsetAsync(deg, 0, NN * sizeof(float), stream);
    hipMemsetAsync(prop, 0, (size_t)NN * FD * sizeof(float), stream);

    deg_kernel<<<(NE + 255) / 256, 256, 0, stream>>>(row, cv, deg);
    dinv_kernel<<<(NN + 255) / 256, 256, 0, stream>>>(deg);

    // one wave per edge, 4 waves per block
    scatter_kernel<<<(NE + 3) / 4, 256, 0, stream>>>(row, col, cv, deg, x, prop);

    dim3 ggrid(NN / 16, 4);
    gemm_kernel<<<ggrid, 256, 0, stream>>>(prop, W, b, out);
}

// Round 2
// 348.516 us; speedup vs baseline: 8.3138x; 8.3138x over previous
//
#include <hip/hip_runtime.h>
#include <hip/hip_bf16.h>

#define NN 50000
#define NE 800000
#define FD 256
#define NN_PAD 50048   // NN rounded to multiple of 64

typedef __attribute__((ext_vector_type(8))) short bf16x8;
typedef __attribute__((ext_vector_type(4))) float f32x4;

__device__ __forceinline__ short f2bf(float f) {
    union { float f; unsigned u; } v; v.f = f;
    unsigned r = v.u + 0x7fffu + ((v.u >> 16) & 1u);
    return (short)(r >> 16);
}

// counts[row]++ ; deg[row] += cv
__global__ void count_deg_kernel(const int* __restrict__ row, const float* __restrict__ cv,
                                 int* __restrict__ counts, float* __restrict__ deg) {
    int e = blockIdx.x * blockDim.x + threadIdx.x;
    if (e < NE) {
        int r = row[e];
        atomicAdd(&counts[r], 1);
        atomicAdd(&deg[r], cv[e]);
    }
}

__global__ void dinv_kernel(float* __restrict__ deg) {
    int i = blockIdx.x * blockDim.x + threadIdx.x;
    if (i < NN) { float d = deg[i]; deg[i] = d > 0.f ? rsqrtf(d) : 0.f; }
}

// exclusive scan of counts[NN] -> rs[NN+1]; single block, 1024 threads,
// each thread serially owns 49 contiguous elements; wave-shfl scan of thread sums.
__global__ void scan_kernel(const int* __restrict__ counts, int* __restrict__ rs) {
    const int PER = 49;  // 1024*49 >= 50000
    __shared__ int wsum[16];
    int tid = threadIdx.x, lane = tid & 63, wv = tid >> 6;
    int base = tid * PER;
    int vals[PER];
    int local = 0;
#pragma unroll
    for (int k = 0; k < PER; ++k) {
        int i = base + k;
        int v = (i < NN) ? counts[i] : 0;
        vals[k] = v; local += v;
    }
    int incl = local;
#pragma unroll
    for (int off = 1; off < 64; off <<= 1) {
        int t = __shfl_up(incl, off, 64);
        if (lane >= off) incl += t;
    }
    if (lane == 63) wsum[wv] = incl;
    __syncthreads();
    if (wv == 0) {
        int s = (lane < 16) ? wsum[lane] : 0;
#pragma unroll
        for (int off = 1; off < 16; off <<= 1) {
            int t = __shfl_up(s, off, 64);
            if (lane >= off) s += t;
        }
        if (lane < 16) wsum[lane] = s;   // inclusive wave prefix
    }
    __syncthreads();
    int woff = (wv == 0) ? 0 : wsum[wv - 1];
    int excl = woff + incl - local;
#pragma unroll
    for (int k = 0; k < PER; ++k) {
        int i = base + k;
        if (i < NN) { rs[i] = excl; excl += vals[k]; }
    }
    if (tid == 1023) rs[NN] = excl;   // == NE
}

// counting-sort edges by destination row; precompute normalized weight
__global__ void bucket_kernel(const int* __restrict__ row, const int* __restrict__ col,
                              const float* __restrict__ cv, const float* __restrict__ dinv,
                              const int* __restrict__ rs, int* __restrict__ cursor,
                              int* __restrict__ e_col, float* __restrict__ e_w) {
    int e = blockIdx.x * blockDim.x + threadIdx.x;
    if (e >= NE) return;
    int r = row[e], c = col[e];
    int pos = atomicAdd(&cursor[r], 1);
    int idx = rs[r] + pos;
    e_col[idx] = c;
    e_w[idx] = dinv[r] * cv[e] * dinv[c];
}

// W fp32 -> bf16
__global__ void wconv_kernel(const float* __restrict__ W, short* __restrict__ Wb) {
    int i = blockIdx.x * blockDim.x + threadIdx.x;   // 65536 threads
    Wb[i] = f2bf(W[i]);
}

// fused gather (CSR) + GEMM: block = 16 node rows, 256 threads (4 waves).
// gather: wave handles 4 nodes, 64 lanes x float4 = 256 feats each; bf16 to LDS.
// gemm: wave w computes out[16 x 64] slice via 16x16x32 bf16 MFMA.
__global__ __launch_bounds__(256) void fused_kernel(
        const float* __restrict__ x, const int* __restrict__ e_col,
        const float* __restrict__ e_w, const int* __restrict__ rs,
        const short* __restrict__ Wb, const float* __restrict__ bias,
        float* __restrict__ out) {
    __shared__ short A[16][264];   // +8 pad to break bank alignment
    int tid = threadIdx.x, lane = tid & 63, wv = tid >> 6;
    int nbase = blockIdx.x * 16;

    // ---- gather phase ----
#pragma unroll
    for (int j = 0; j < 4; ++j) {
        int n = nbase + wv * 4 + j;
        int s = rs[n], en = rs[n + 1];
        float4 acc = {0.f, 0.f, 0.f, 0.f};
        if (s < en) {
            int c = e_col[s];
            float w = e_w[s];
            for (int e = s; e < en; ++e) {
                int cn = 0; float wn = 0.f;
                if (e + 1 < en) { cn = e_col[e + 1]; wn = e_w[e + 1]; }   // prefetch
                float4 v = *(const float4*)(x + (size_t)c * FD + lane * 4);
                acc.x += w * v.x; acc.y += w * v.y; acc.z += w * v.z; acc.w += w * v.w;
                c = cn; w = wn;
            }
        }
        short* ap = &A[wv * 4 + j][lane * 4];
        ap[0] = f2bf(acc.x); ap[1] = f2bf(acc.y); ap[2] = f2bf(acc.z); ap[3] = f2bf(acc.w);
    }
    __syncthreads();

    // ---- GEMM phase: out[nbase..+16][wv*64..+64] ----
    int m = lane & 15, g = lane >> 4;
    f32x4 acc0 = {0,0,0,0}, acc1 = {0,0,0,0}, acc2 = {0,0,0,0}, acc3 = {0,0,0,0};
    const short* w0 = Wb + (size_t)(wv * 64 + 0  + m) * FD;
    const short* w1 = Wb + (size_t)(wv * 64 + 16 + m) * FD;
    const short* w2 = Wb + (size_t)(wv * 64 + 32 + m) * FD;
    const short* w3 = Wb + (size_t)(wv * 64 + 48 + m) * FD;
#pragma unroll
    for (int ks = 0; ks < 8; ++ks) {
        int ko = ks * 32 + g * 8;
        bf16x8 af = *(const bf16x8*)&A[m][ko];
        bf16x8 b0 = *(const bf16x8*)(w0 + ko);
        bf16x8 b1 = *(const bf16x8*)(w1 + ko);
        bf16x8 b2 = *(const bf16x8*)(w2 + ko);
        bf16x8 b3 = *(const bf16x8*)(w3 + ko);
        acc0 = __builtin_amdgcn_mfma_f32_16x16x32_bf16(af, b0, acc0, 0, 0, 0);
        acc1 = __builtin_amdgcn_mfma_f32_16x16x32_bf16(af, b1, acc1, 0, 0, 0);
        acc2 = __builtin_amdgcn_mfma_f32_16x16x32_bf16(af, b2, acc2, 0, 0, 0);
        acc3 = __builtin_amdgcn_mfma_f32_16x16x32_bf16(af, b3, acc3, 0, 0, 0);
    }
    // D: col = lane&15 (within tile), row = g*4 + r
#pragma unroll
    for (int nt = 0; nt < 4; ++nt) {
        f32x4 a = nt == 0 ? acc0 : nt == 1 ? acc1 : nt == 2 ? acc2 : acc3;
        int c = wv * 64 + nt * 16 + m;
        float bv = bias[c];
#pragma unroll
        for (int r = 0; r < 4; ++r) {
            out[(size_t)(nbase + g * 4 + r) * FD + c] = a[r] + bv;
        }
    }
}

extern "C" void kernel_launch(void* const* d_in, const int* in_sizes, int n_in,
                              void* d_out, int out_size, void* d_ws, size_t ws_size,
                              hipStream_t stream) {
    const float* x  = (const float*)d_in[0];
    const int*   ei = (const int*)d_in[1];
    const float* cv = (const float*)d_in[2];
    const float* W  = (const float*)d_in[3];
    const float* b  = (const float*)d_in[4];
    float* out = (float*)d_out;

    const int* row = ei;
    const int* col = ei + NE;

    // ws layout
    float* deg    = (float*)d_ws;                 // NN_PAD
    int*   counts = (int*)(deg + NN_PAD);         // NN_PAD
    int*   rs     = counts + NN_PAD;              // NN_PAD (uses NN+1)
    int*   cursor = rs + NN_PAD;                  // NN_PAD
    int*   e_col  = cursor + NN_PAD;              // NE
    float* e_w    = (float*)(e_col + NE);         // NE
    short* Wb     = (short*)(e_w + NE);           // FD*FD

    hipMemsetAsync(deg, 0, NN_PAD * sizeof(float), stream);
    hipMemsetAsync(counts, 0, NN_PAD * sizeof(int), stream);
    hipMemsetAsync(cursor, 0, NN_PAD * sizeof(int), stream);

    count_deg_kernel<<<(NE + 255) / 256, 256, 0, stream>>>(row, cv, counts, deg);
    dinv_kernel<<<(NN + 255) / 256, 256, 0, stream>>>(deg);
    scan_kernel<<<1, 1024, 0, stream>>>(counts, rs);
    bucket_kernel<<<(NE + 255) / 256, 256, 0, stream>>>(row, col, cv, deg, rs, cursor, e_col, e_w);
    wconv_kernel<<<(FD * FD) / 256, 256, 0, stream>>>(W, Wb);

    fused_kernel<<<NN / 16, 256, 0, stream>>>(x, e_col, e_w, rs, Wb, b, out);
}

// Round 3
// 259.838 us; speedup vs baseline: 11.1511x; 1.3413x over previous
//
#include <hip/hip_runtime.h>
#include <hip/hip_bf16.h>

#define NN 50000
#define NE 800000
#define FD 256
#define NN_PAD 50048       // NN rounded up to multiple of 64
#define SCAN_B 196         // ceil(NN/256)

typedef __attribute__((ext_vector_type(8))) short bf16x8;
typedef __attribute__((ext_vector_type(4))) float f32x4;

__device__ __forceinline__ short f2bf(float f) {
    union { float f; unsigned u; } v; v.f = f;
    unsigned r = v.u + 0x7fffu + ((v.u >> 16) & 1u);
    return (short)(r >> 16);
}
__device__ __forceinline__ float bf2f(unsigned short u) {
    union { unsigned u; float f; } v; v.u = ((unsigned)u) << 16;
    return v.f;
}

// ---- fp32 -> bf16 conversion for x and W in one kernel ----
__global__ void convert_kernel(const float* __restrict__ x, const float* __restrict__ W,
                               short* __restrict__ xb, short* __restrict__ Wb) {
    size_t i = ((size_t)blockIdx.x * blockDim.x + threadIdx.x) * 4;
    const size_t NX = (size_t)NN * FD;
    if (i < NX) {
        float4 v = *(const float4*)(x + i);
        short* d = xb + i;
        d[0] = f2bf(v.x); d[1] = f2bf(v.y); d[2] = f2bf(v.z); d[3] = f2bf(v.w);
    } else {
        size_t j = i - NX;
        if (j < (size_t)FD * FD) {
            float4 v = *(const float4*)(W + j);
            short* d = Wb + j;
            d[0] = f2bf(v.x); d[1] = f2bf(v.y); d[2] = f2bf(v.z); d[3] = f2bf(v.w);
        }
    }
}

// counts[row]++ ; deg[row] += cv
__global__ void count_deg_kernel(const int* __restrict__ row, const float* __restrict__ cv,
                                 int* __restrict__ counts, float* __restrict__ deg) {
    int e = blockIdx.x * blockDim.x + threadIdx.x;
    if (e < NE) {
        int r = row[e];
        atomicAdd(&counts[r], 1);
        atomicAdd(&deg[r], cv[e]);
    }
}

__device__ __forceinline__ int block_excl_scan256(int v, int tid) {
    __shared__ int ws[4];
    int lane = tid & 63, wv = tid >> 6;
    int incl = v;
#pragma unroll
    for (int off = 1; off < 64; off <<= 1) {
        int t = __shfl_up(incl, off);
        if (lane >= off) incl += t;
    }
    if (lane == 63) ws[wv] = incl;
    __syncthreads();
    int acc = 0;
#pragma unroll
    for (int k = 0; k < 4; ++k) if (k < wv) acc += ws[k];
    return acc + incl - v;
}

// per-block sums of counts -> bsum; also deg -> deg^-1/2 in place
__global__ void sum_dinv_kernel(const int* __restrict__ counts, float* __restrict__ deg,
                                int* __restrict__ bsum) {
    int i = blockIdx.x * 256 + threadIdx.x;
    int v = (i < NN) ? counts[i] : 0;
    int lane = threadIdx.x & 63, wv = threadIdx.x >> 6;
    int s = v;
#pragma unroll
    for (int off = 1; off < 64; off <<= 1) s += __shfl_xor(s, off);
    __shared__ int ws[4];
    if (lane == 0) ws[wv] = s;
    __syncthreads();
    if (threadIdx.x == 0) bsum[blockIdx.x] = ws[0] + ws[1] + ws[2] + ws[3];
    if (i < NN) { float d = deg[i]; deg[i] = d > 0.f ? rsqrtf(d) : 0.f; }
}

// exclusive scan of bsum[SCAN_B] in place (single block, 256 threads)
__global__ void scan_bsum_kernel(int* __restrict__ bsum) {
    int tid = threadIdx.x;
    int v = (tid < SCAN_B) ? bsum[tid] : 0;
    int excl = block_excl_scan256(v, tid);
    if (tid < SCAN_B) bsum[tid] = excl;
}

// rs[i] = bsum[blk] + block-exclusive-scan(counts); cursor = rs; rs[NN] = NE
__global__ void write_rs_kernel(const int* __restrict__ counts, const int* __restrict__ bsum,
                                int* __restrict__ rs, int* __restrict__ cursor) {
    int i = blockIdx.x * 256 + threadIdx.x;
    int v = (i < NN) ? counts[i] : 0;
    int excl = block_excl_scan256(v, threadIdx.x) + bsum[blockIdx.x];
    if (i < NN) { rs[i] = excl; cursor[i] = excl; }
    if (i == NN - 1) rs[NN] = excl + v;
}

// counting-sort edges by destination; pack (col, w) into 8 bytes
__global__ void bucket_kernel(const int* __restrict__ row, const int* __restrict__ col,
                              const float* __restrict__ cv, const float* __restrict__ dinv,
                              int* __restrict__ cursor, unsigned long long* __restrict__ e_cw) {
    int e = blockIdx.x * blockDim.x + threadIdx.x;
    if (e >= NE) return;
    int r = row[e], c = col[e];
    float w = dinv[r] * cv[e] * dinv[c];
    int idx = atomicAdd(&cursor[r], 1);
    union { float f; unsigned u; } wu; wu.f = w;
    e_cw[idx] = ((unsigned long long)wu.u << 32) | (unsigned)c;
}

// fused gather (CSR, bf16 x) + GEMM
__global__ __launch_bounds__(256) void fused_kernel(
        const short* __restrict__ xb, const unsigned long long* __restrict__ e_cw,
        const int* __restrict__ rs, const short* __restrict__ Wb,
        const float* __restrict__ bias, float* __restrict__ out) {
    __shared__ short A[16][264];
    int tid = threadIdx.x, lane = tid & 63, wv = tid >> 6;
    int nbase = blockIdx.x * 16;

    // ---- gather: wave handles 4 nodes; per edge, 64 lanes x 4 bf16 = 256 feats
#pragma unroll
    for (int j = 0; j < 4; ++j) {
        int n = nbase + wv * 4 + j;
        int s = rs[n], en = rs[n + 1];
        float4 a0 = {0.f, 0.f, 0.f, 0.f};
        float4 a1 = {0.f, 0.f, 0.f, 0.f};
        int e = s;
        for (; e + 2 <= en; e += 2) {
            unsigned long long cw0 = e_cw[e], cw1 = e_cw[e + 1];
            int c0 = (int)(unsigned)cw0, c1 = (int)(unsigned)cw1;
            union { unsigned u; float f; } u0, u1;
            u0.u = (unsigned)(cw0 >> 32); u1.u = (unsigned)(cw1 >> 32);
            ushort4 v0 = *(const ushort4*)(xb + (size_t)c0 * FD + lane * 4);
            ushort4 v1 = *(const ushort4*)(xb + (size_t)c1 * FD + lane * 4);
            a0.x += u0.f * bf2f(v0.x); a0.y += u0.f * bf2f(v0.y);
            a0.z += u0.f * bf2f(v0.z); a0.w += u0.f * bf2f(v0.w);
            a1.x += u1.f * bf2f(v1.x); a1.y += u1.f * bf2f(v1.y);
            a1.z += u1.f * bf2f(v1.z); a1.w += u1.f * bf2f(v1.w);
        }
        if (e < en) {
            unsigned long long cw0 = e_cw[e];
            int c0 = (int)(unsigned)cw0;
            union { unsigned u; float f; } u0; u0.u = (unsigned)(cw0 >> 32);
            ushort4 v0 = *(const ushort4*)(xb + (size_t)c0 * FD + lane * 4);
            a0.x += u0.f * bf2f(v0.x); a0.y += u0.f * bf2f(v0.y);
            a0.z += u0.f * bf2f(v0.z); a0.w += u0.f * bf2f(v0.w);
        }
        a0.x += a1.x; a0.y += a1.y; a0.z += a1.z; a0.w += a1.w;
        short* ap = &A[wv * 4 + j][lane * 4];
        ap[0] = f2bf(a0.x); ap[1] = f2bf(a0.y); ap[2] = f2bf(a0.z); ap[3] = f2bf(a0.w);
    }
    __syncthreads();

    // ---- GEMM: out[nbase..+16][wv*64..+64] via 16x16x32 bf16 MFMA
    int m = lane & 15, g = lane >> 4;
    f32x4 acc0 = {0,0,0,0}, acc1 = {0,0,0,0}, acc2 = {0,0,0,0}, acc3 = {0,0,0,0};
    const short* w0 = Wb + (size_t)(wv * 64 + 0  + m) * FD;
    const short* w1 = Wb + (size_t)(wv * 64 + 16 + m) * FD;
    const short* w2 = Wb + (size_t)(wv * 64 + 32 + m) * FD;
    const short* w3 = Wb + (size_t)(wv * 64 + 48 + m) * FD;
#pragma unroll
    for (int ks = 0; ks < 8; ++ks) {
        int ko = ks * 32 + g * 8;
        bf16x8 af = *(const bf16x8*)&A[m][ko];
        bf16x8 b0 = *(const bf16x8*)(w0 + ko);
        bf16x8 b1 = *(const bf16x8*)(w1 + ko);
        bf16x8 b2 = *(const bf16x8*)(w2 + ko);
        bf16x8 b3 = *(const bf16x8*)(w3 + ko);
        acc0 = __builtin_amdgcn_mfma_f32_16x16x32_bf16(af, b0, acc0, 0, 0, 0);
        acc1 = __builtin_amdgcn_mfma_f32_16x16x32_bf16(af, b1, acc1, 0, 0, 0);
        acc2 = __builtin_amdgcn_mfma_f32_16x16x32_bf16(af, b2, acc2, 0, 0, 0);
        acc3 = __builtin_amdgcn_mfma_f32_16x16x32_bf16(af, b3, acc3, 0, 0, 0);
    }
#pragma unroll
    for (int nt = 0; nt < 4; ++nt) {
        f32x4 a = nt == 0 ? acc0 : nt == 1 ? acc1 : nt == 2 ? acc2 : acc3;
        int c = wv * 64 + nt * 16 + m;
        float bv = bias[c];
#pragma unroll
        for (int r = 0; r < 4; ++r) {
            out[(size_t)(nbase + g * 4 + r) * FD + c] = a[r] + bv;
        }
    }
}

extern "C" void kernel_launch(void* const* d_in, const int* in_sizes, int n_in,
                              void* d_out, int out_size, void* d_ws, size_t ws_size,
                              hipStream_t stream) {
    const float* x  = (const float*)d_in[0];
    const int*   ei = (const int*)d_in[1];
    const float* cv = (const float*)d_in[2];
    const float* W  = (const float*)d_in[3];
    const float* b  = (const float*)d_in[4];
    float* out = (float*)d_out;

    const int* row = ei;
    const int* col = ei + NE;

    // ws layout (all 8B-aligned where needed)
    float* deg    = (float*)d_ws;                         // NN_PAD
    int*   counts = (int*)(deg + NN_PAD);                 // NN_PAD
    int*   rs     = counts + NN_PAD;                      // NN_PAD (uses NN+1)
    int*   cursor = rs + NN_PAD;                          // NN_PAD
    int*   bsum   = cursor + NN_PAD;                      // 256
    unsigned long long* e_cw = (unsigned long long*)(bsum + 256);   // NE * 8B
    short* xb     = (short*)(e_cw + NE);                  // NN*FD
    short* Wb     = xb + (size_t)NN * FD;                 // FD*FD

    hipMemsetAsync(deg, 0, NN_PAD * sizeof(float), stream);
    hipMemsetAsync(counts, 0, NN_PAD * sizeof(int), stream);

    const size_t NCONV = ((size_t)NN * FD + (size_t)FD * FD) / 4;
    convert_kernel<<<(NCONV + 255) / 256, 256, 0, stream>>>(x, W, xb, Wb);
    count_deg_kernel<<<(NE + 255) / 256, 256, 0, stream>>>(row, cv, counts, deg);
    sum_dinv_kernel<<<SCAN_B, 256, 0, stream>>>(counts, deg, bsum);
    scan_bsum_kernel<<<1, 256, 0, stream>>>(bsum);
    write_rs_kernel<<<SCAN_B, 256, 0, stream>>>(counts, bsum, rs, cursor);
    bucket_kernel<<<(NE + 255) / 256, 256, 0, stream>>>(row, col, cv, deg, cursor, e_cw);

    fused_kernel<<<NN / 16, 256, 0, stream>>>(xb, e_cw, rs, Wb, b, out);
}

// Round 4
// 220.428 us; speedup vs baseline: 13.1448x; 1.1788x over previous
//
#include <hip/hip_runtime.h>
#include <hip/hip_bf16.h>

#define NN 50000
#define NE 800000
#define FD 256
#define NN_PAD 50048       // NN rounded up to multiple of 64
#define SCAN_B 196         // ceil(NN/256)

typedef __attribute__((ext_vector_type(8))) short bf16x8;
typedef __attribute__((ext_vector_type(16))) short short16;
typedef __attribute__((ext_vector_type(4))) float f32x4;
typedef unsigned long long ull;

__device__ __forceinline__ short f2bf(float f) {
    union { float f; unsigned u; } v; v.f = f;
    unsigned r = v.u + 0x7fffu + ((v.u >> 16) & 1u);
    return (short)(r >> 16);
}
__device__ __forceinline__ float bf2f(unsigned short u) {
    union { unsigned u; float f; } v; v.u = ((unsigned)u) << 16;
    return v.f;
}

// dc[row] += (1<<40) | fix24(cv)   -- one 64b atomic per edge
__global__ void count_deg_kernel(const int* __restrict__ row, const float* __restrict__ cv,
                                 ull* __restrict__ dc) {
    int e = blockIdx.x * blockDim.x + threadIdx.x;
    if (e < NE) {
        int r = row[e];
        unsigned cf = (unsigned)(cv[e] * 16777216.0f + 0.5f);
        atomicAdd(&dc[r], (1ULL << 40) | (ull)cf);
    }
}

__device__ __forceinline__ int block_excl_scan256(int v, int tid) {
    __shared__ int ws[4];
    int lane = tid & 63, wv = tid >> 6;
    int incl = v;
#pragma unroll
    for (int off = 1; off < 64; off <<= 1) {
        int t = __shfl_up(incl, off);
        if (lane >= off) incl += t;
    }
    if (lane == 63) ws[wv] = incl;
    __syncthreads();
    int acc = 0;
#pragma unroll
    for (int k = 0; k < 4; ++k) if (k < wv) acc += ws[k];
    return acc + incl - v;
}

// per-block count sums -> bsum; dinv = deg^-1/2 (0 if deg==0)
__global__ void sum_dinv_kernel(const ull* __restrict__ dc, float* __restrict__ dinv,
                                int* __restrict__ bsum) {
    int i = blockIdx.x * 256 + threadIdx.x;
    ull v = (i < NN) ? dc[i] : 0ULL;
    int cnt = (int)(v >> 40);
    ull df = v & ((1ULL << 40) - 1);
    int lane = threadIdx.x & 63, wv = threadIdx.x >> 6;
    int s = cnt;
#pragma unroll
    for (int off = 1; off < 64; off <<= 1) s += __shfl_xor(s, off);
    __shared__ int ws[4];
    if (lane == 0) ws[wv] = s;
    __syncthreads();
    if (threadIdx.x == 0) bsum[blockIdx.x] = ws[0] + ws[1] + ws[2] + ws[3];
    if (i < NN) {
        float d = (float)df * (1.0f / 16777216.0f);
        dinv[i] = (df > 0) ? rsqrtf(d) : 0.f;
    }
}

__global__ void scan_bsum_kernel(int* __restrict__ bsum) {
    int tid = threadIdx.x;
    int v = (tid < SCAN_B) ? bsum[tid] : 0;
    int excl = block_excl_scan256(v, tid);
    if (tid < SCAN_B) bsum[tid] = excl;
}

__global__ void write_rs_kernel(const ull* __restrict__ dc, const int* __restrict__ bsum,
                                int* __restrict__ rs, int* __restrict__ cursor) {
    int i = blockIdx.x * 256 + threadIdx.x;
    int v = (i < NN) ? (int)(dc[i] >> 40) : 0;
    int excl = block_excl_scan256(v, threadIdx.x) + bsum[blockIdx.x];
    if (i < NN) { rs[i] = excl; cursor[i] = excl; }
    if (i == NN - 1) rs[NN] = excl + v;
}

// xbs = bf16(x * dinv[row]); Wb = bf16(W)
__global__ void convert_kernel(const float* __restrict__ x, const float* __restrict__ W,
                               const float* __restrict__ dinv,
                               short* __restrict__ xbs, short* __restrict__ Wb) {
    size_t i = ((size_t)blockIdx.x * blockDim.x + threadIdx.x) * 4;
    const size_t NX = (size_t)NN * FD;
    if (i < NX) {
        float dr = dinv[i >> 8];
        float4 v = *(const float4*)(x + i);
        short* d = xbs + i;
        d[0] = f2bf(v.x * dr); d[1] = f2bf(v.y * dr);
        d[2] = f2bf(v.z * dr); d[3] = f2bf(v.w * dr);
    } else {
        size_t j = i - NX;
        if (j < (size_t)FD * FD) {
            float4 v = *(const float4*)(W + j);
            short* d = Wb + j;
            d[0] = f2bf(v.x); d[1] = f2bf(v.y); d[2] = f2bf(v.z); d[3] = f2bf(v.w);
        }
    }
}

// counting-sort edges by destination; store (cv_bits, col)
__global__ void bucket_kernel(const int* __restrict__ row, const int* __restrict__ col,
                              const float* __restrict__ cv,
                              int* __restrict__ cursor, ull* __restrict__ e_cw) {
    int e = blockIdx.x * blockDim.x + threadIdx.x;
    if (e >= NE) return;
    int r = row[e], c = col[e];
    int idx = atomicAdd(&cursor[r], 1);
    union { float f; unsigned u; } wu; wu.f = cv[e];
    e_cw[idx] = ((ull)wu.u << 32) | (unsigned)c;
}

// fused gather + GEMM. Block = 16 nodes, 4 waves.
// Gather: wave handles 4 nodes IN PARALLEL (quad q = 16 lanes per node),
// lane i of quad loads 16 bf16 feats (32B). 4 independent load chains/wave.
__global__ __launch_bounds__(256) void fused_kernel(
        const short* __restrict__ xbs, const ull* __restrict__ e_cw,
        const int* __restrict__ rs, const float* __restrict__ dinv,
        const short* __restrict__ Wb, const float* __restrict__ bias,
        float* __restrict__ out) {
    __shared__ short A[16][264];
    int tid = threadIdx.x, lane = tid & 63, wv = tid >> 6;
    int q = lane >> 4, i = lane & 15;
    int nbase = blockIdx.x * 16;
    int n = nbase + wv * 4 + q;

    int s = rs[n], en = rs[n + 1];
    float dr = dinv[n];
    float acc[16];
#pragma unroll
    for (int k = 0; k < 16; ++k) acc[k] = 0.f;

    const short* xb_i = xbs + i * 16;
    int e = s;
    for (; e + 2 <= en; e += 2) {
        ull cw0 = e_cw[e], cw1 = e_cw[e + 1];
        int c0 = (int)(unsigned)cw0, c1 = (int)(unsigned)cw1;
        union { unsigned u; float f; } u0, u1;
        u0.u = (unsigned)(cw0 >> 32); u1.u = (unsigned)(cw1 >> 32);
        short16 v0 = *(const short16*)(xb_i + (size_t)c0 * FD);
        short16 v1 = *(const short16*)(xb_i + (size_t)c1 * FD);
#pragma unroll
        for (int k = 0; k < 16; ++k) acc[k] += u0.f * bf2f((unsigned short)v0[k]);
#pragma unroll
        for (int k = 0; k < 16; ++k) acc[k] += u1.f * bf2f((unsigned short)v1[k]);
    }
    if (e < en) {
        ull cw0 = e_cw[e];
        int c0 = (int)(unsigned)cw0;
        union { unsigned u; float f; } u0; u0.u = (unsigned)(cw0 >> 32);
        short16 v0 = *(const short16*)(xb_i + (size_t)c0 * FD);
#pragma unroll
        for (int k = 0; k < 16; ++k) acc[k] += u0.f * bf2f((unsigned short)v0[k]);
    }

    bf16x8 lo, hi;
#pragma unroll
    for (int k = 0; k < 8; ++k) {
        lo[k] = f2bf(acc[k] * dr);
        hi[k] = f2bf(acc[k + 8] * dr);
    }
    *(bf16x8*)&A[wv * 4 + q][i * 16] = lo;
    *(bf16x8*)&A[wv * 4 + q][i * 16 + 8] = hi;
    __syncthreads();

    // ---- GEMM: out[nbase..+16][wv*64..+64] via 16x16x32 bf16 MFMA
    int m = lane & 15, g = lane >> 4;
    f32x4 acc0 = {0,0,0,0}, acc1 = {0,0,0,0}, acc2 = {0,0,0,0}, acc3 = {0,0,0,0};
    const short* w0 = Wb + (size_t)(wv * 64 + 0  + m) * FD;
    const short* w1 = Wb + (size_t)(wv * 64 + 16 + m) * FD;
    const short* w2 = Wb + (size_t)(wv * 64 + 32 + m) * FD;
    const short* w3 = Wb + (size_t)(wv * 64 + 48 + m) * FD;
#pragma unroll
    for (int ks = 0; ks < 8; ++ks) {
        int ko = ks * 32 + g * 8;
        bf16x8 af = *(const bf16x8*)&A[m][ko];
        bf16x8 b0 = *(const bf16x8*)(w0 + ko);
        bf16x8 b1 = *(const bf16x8*)(w1 + ko);
        bf16x8 b2 = *(const bf16x8*)(w2 + ko);
        bf16x8 b3 = *(const bf16x8*)(w3 + ko);
        acc0 = __builtin_amdgcn_mfma_f32_16x16x32_bf16(af, b0, acc0, 0, 0, 0);
        acc1 = __builtin_amdgcn_mfma_f32_16x16x32_bf16(af, b1, acc1, 0, 0, 0);
        acc2 = __builtin_amdgcn_mfma_f32_16x16x32_bf16(af, b2, acc2, 0, 0, 0);
        acc3 = __builtin_amdgcn_mfma_f32_16x16x32_bf16(af, b3, acc3, 0, 0, 0);
    }
#pragma unroll
    for (int nt = 0; nt < 4; ++nt) {
        f32x4 a = nt == 0 ? acc0 : nt == 1 ? acc1 : nt == 2 ? acc2 : acc3;
        int c = wv * 64 + nt * 16 + m;
        float bv = bias[c];
#pragma unroll
        for (int r = 0; r < 4; ++r) {
            out[(size_t)(nbase + g * 4 + r) * FD + c] = a[r] + bv;
        }
    }
}

extern "C" void kernel_launch(void* const* d_in, const int* in_sizes, int n_in,
                              void* d_out, int out_size, void* d_ws, size_t ws_size,
                              hipStream_t stream) {
    const float* x  = (const float*)d_in[0];
    const int*   ei = (const int*)d_in[1];
    const float* cv = (const float*)d_in[2];
    const float* W  = (const float*)d_in[3];
    const float* b  = (const float*)d_in[4];
    float* out = (float*)d_out;

    const int* row = ei;
    const int* col = ei + NE;

    // ws layout: 32B-aligned chain: dc | e_cw | xbs | Wb | dinv | rs | cursor | bsum
    ull*   dc     = (ull*)d_ws;                            // NN_PAD * 8B
    ull*   e_cw   = dc + NN_PAD;                           // NE * 8B
    short* xbs    = (short*)(e_cw + NE);                   // NN*FD * 2B
    short* Wb     = xbs + (size_t)NN * FD;                 // FD*FD * 2B
    float* dinv   = (float*)(Wb + (size_t)FD * FD);        // NN_PAD
    int*   rs     = (int*)(dinv + NN_PAD);                 // NN_PAD (uses NN+1)
    int*   cursor = rs + NN_PAD;                           // NN_PAD
    int*   bsum   = cursor + NN_PAD;                       // 256

    hipMemsetAsync(dc, 0, NN_PAD * sizeof(ull), stream);

    count_deg_kernel<<<(NE + 255) / 256, 256, 0, stream>>>(row, cv, dc);
    sum_dinv_kernel<<<SCAN_B, 256, 0, stream>>>(dc, dinv, bsum);
    scan_bsum_kernel<<<1, 256, 0, stream>>>(bsum);
    write_rs_kernel<<<SCAN_B, 256, 0, stream>>>(dc, bsum, rs, cursor);
    const size_t NCONV = ((size_t)NN * FD + (size_t)FD * FD) / 4;
    convert_kernel<<<(NCONV + 255) / 256, 256, 0, stream>>>(x, W, dinv, xbs, Wb);
    bucket_kernel<<<(NE + 255) / 256, 256, 0, stream>>>(row, col, cv, cursor, e_cw);

    fused_kernel<<<NN / 16, 256, 0, stream>>>(xbs, e_cw, rs, dinv, Wb, b, out);
}